// Round 6
// baseline (1852.143 us; speedup 1.0000x reference)
//
#include <hip/hip_runtime.h>

// EqProp MLP relaxation (784->128->128->10, B=16384, T=60), FUSED all-FP32 kernel.
// PRECISION FINDING (prev session): W1 ~ N(0,1/128) puts the tanh relaxation at
// the edge of chaos; (I-J)^-1 amplifies bias ~260x; per-step state quantization
// accumulates. Everything stays fp32-grade.
// R5 POST-MORTEM: swizzle fixed (conflicts 1.26e8->8e3), 2 waves/SIMD, 1385us.
// dur/step/CU ~61k cy vs ~20-33k cy floors on VALU and LDS: NEITHER pipe
// saturated -> phase-correlation. Per chunk: 16 ds_read_b128 then 144
// dependent FMAs; 2 waves/SIMD in barrier lockstep are usually in the SAME
// phase -> LDS idles during FMA bursts, VALU idles during read bursts.
// R6: explicit 2-deep SOFTWARE PIPELINE. A/B operand register buffers
// (static indexing only); prefetch chunk c+1 (16 b128 + w2r global) while
// chunk c's FMAs run. Compiler emits counted lgkmcnt waits -> LDS/VALU
// overlap within one wave, independent of occupancy. VGPR ~210-230 <= 256
// keeps 2 waves/SIMD. Geometry unchanged from R5:
//   ROWS=64, NT=512 (8 waves), 4x4 thread tiles, grid=256 = 1 block/CU,
//   LDS = 64K W1 (full-period chunk swizzle) + 32K h1 + 32K h2 = 128KB.
//   Swizzle: chunk of W1[r][c] at (r<<5)|((c>>2)^(r>>2)); both GEMM read
//   patterns use the same offset co=(jg^c)<<2 and are conflict-free.
//   h1' = tanh(c1 + h2@W1)          c1 = x@W0^T+b0 in REGISTERS (loop-invariant)
//   h2' = tanh(b1 + h1@W1^T + h3@W2)   h3 state in REGISTERS (lanes jg<10,
//   h3' = tanh(b2 + h2@W2^T)           broadcast via __shfl width=32)

#define NB 16384
#define D0 784
#define D1 128
#define D3 10
#define TSTEPS 60
#define NT 512
#define ROWS 64
#define NBLK (NB / ROWS)                 // 256 blocks = 1 per CU
#define H2O ((size_t)NB * D1)
#define H3O ((size_t)2 * NB * D1)
#define XS_LD 68   // padded x-staging stride, 16B-aligned rows

__device__ __forceinline__ float ftanh(float x)
{
    // tanh(x) = 1 - 2/(exp(2x)+1); safe at +/-inf (rcp(inf)=0 -> 1; e->0 -> -1)
    float e = __expf(2.0f * x);                  // v_mul + v_exp_f32
    float r = __builtin_amdgcn_rcpf(e + 1.0f);   // v_rcp_f32, ~1 ulp
    return fmaf(-2.0f, r, 1.0f);
}

union F4 { float4 v; float f[4]; };

// Load all operands of chunk c_ into a named register buffer set.
#define LOADCH(P2, P1, WA, WB, W2R, c_) do {                                   \
    const int k_  = (c_) << 2;                                                 \
    const int co_ = ((jg ^ (c_)) << 2);                                        \
    _Pragma("unroll") for (int i_ = 0; i_ < 4; ++i_) {                         \
        P2[i_].v = *(const float4*)&h2L[(r0 + i_) * D1 + k_];                  \
        P1[i_].v = *(const float4*)&h1L[(r0 + i_) * D1 + k_];                  \
    }                                                                          \
    _Pragma("unroll") for (int l_ = 0; l_ < 4; ++l_)                           \
        WB[l_].v = *(const float4*)&W1L[(j0 + l_) * D1 + co_];                 \
    _Pragma("unroll") for (int kk_ = 0; kk_ < 4; ++kk_)                        \
        WA[kk_].v = *(const float4*)&W1L[(k_ + kk_) * D1 + co_];               \
    W2R.v = *(const float4*)(W2 + (size_t)jg3 * D1 + k_);                      \
} while (0)

// 144 FMAs of one chunk (a1 += h2*W1, a2 += h1*W1^T, a3 += h2*W2^T).
#define FMACH(P2, P1, WA, WB, W2R) do {                                        \
    _Pragma("unroll") for (int kk_ = 0; kk_ < 4; ++kk_) {                      \
        _Pragma("unroll") for (int i_ = 0; i_ < 4; ++i_) {                     \
            _Pragma("unroll") for (int l_ = 0; l_ < 4; ++l_) {                 \
                a1[i_][l_] = fmaf(P2[i_].f[kk_], WA[kk_].f[l_], a1[i_][l_]);   \
                a2[i_][l_] = fmaf(P1[i_].f[kk_], WB[l_].f[kk_], a2[i_][l_]);   \
            }                                                                  \
            a3[i_] = fmaf(P2[i_].f[kk_], W2R.f[kk_], a3[i_]);                  \
        }                                                                      \
    }                                                                          \
} while (0)

__global__ __launch_bounds__(NT, 1)      // 1 block/CU -> VGPR cap 256 (2 w/SIMD)
void k_fused(const float* __restrict__ x,
             const float* __restrict__ n1, const float* __restrict__ n2,
             const float* __restrict__ n3,
             const float* __restrict__ W0, const float* __restrict__ b0,
             const float* __restrict__ W1, const float* __restrict__ b1,
             const float* __restrict__ W2, const float* __restrict__ b2,
             float* __restrict__ out)
{
    __shared__ float W1L[D1 * D1];       // 64 KB, full-period chunk swizzle
    __shared__ float h1L[ROWS * D1];     // 32 KB
    __shared__ float h2L[ROWS * D1];     // 32 KB   -> total 131072 B
    float* xs = W1L;                     // x staging aliases W1L (phase 1 only)

    const int tid = threadIdx.x;
    const int jg = tid & 31, rg = tid >> 5;      // jg: col group, rg: 0..15
    const int j0 = jg * 4, r0 = rg * 4;
    const int jg3 = (jg < D3) ? jg : 0;          // clamped W2 row (a3 jg>=10 unused)
    const size_t row0 = (size_t)blockIdx.x * ROWS;

    // ---------------- phase 1: c1 = x @ W0^T + b0, kept in registers
    float c1r[4][4];
    #pragma unroll
    for (int i = 0; i < 4; ++i)
        #pragma unroll
        for (int l = 0; l < 4; ++l) c1r[i][l] = 0.f;

    for (int ch = 0; ch < 13; ++ch) {            // 784 = 12*64 + 16
        const int kb = ch * 64;
        const int klen = (ch < 12) ? 64 : 16;
        const int nv4 = klen >> 2;
        for (int q = tid; q < ROWS * nv4; q += NT) {
            int r = q / nv4, c4 = q - r * nv4;
            *(float4*)&xs[r * XS_LD + 4 * c4] =
                *(const float4*)(x + (row0 + r) * D0 + kb + 4 * c4);
        }
        __syncthreads();
        for (int k = 0; k < klen; k += 4) {
            F4 xr[4];
            #pragma unroll
            for (int i = 0; i < 4; ++i)
                xr[i].v = *(const float4*)&xs[(r0 + i) * XS_LD + k];
            #pragma unroll
            for (int l = 0; l < 4; ++l) {
                F4 w; w.v = *(const float4*)(W0 + (size_t)(j0 + l) * D0 + kb + k);
                #pragma unroll
                for (int kk = 0; kk < 4; ++kk)
                    #pragma unroll
                    for (int i = 0; i < 4; ++i)
                        c1r[i][l] = fmaf(xr[i].f[kk], w.f[kk], c1r[i][l]);
            }
        }
        __syncthreads();                 // last xs read done before W1L stage
    }
    float b1r[4];
    #pragma unroll
    for (int l = 0; l < 4; ++l) {
        float bb = b0[j0 + l];
        #pragma unroll
        for (int i = 0; i < 4; ++i) c1r[i][l] += bb;
        b1r[l] = b1[j0 + l];
    }
    const float b2r = (jg < D3) ? b2[jg] : 0.f;

    // ---------------- stage W1 into LDS (full-period swizzle) + init state
    // chunk of W1[r][c] stored at (r<<5) | ((c>>2) ^ (r>>2)); r>>2 spans 0..31.
    for (int q = tid; q < 4096; q += NT) {       // 8 float4 per thread
        int r = q >> 5, c4 = q & 31;
        int d = (r << 5) | (c4 ^ (r >> 2));
        ((float4*)W1L)[d] = ((const float4*)W1)[q];  // row-perm write: no conflict
    }
    for (int q = tid; q < ROWS * 32; q += NT) {
        int r = q >> 5, c4 = q & 31;
        *(float4*)&h1L[r * D1 + 4 * c4] = *(const float4*)(n1 + (row0 + r) * D1 + 4 * c4);
        *(float4*)&h2L[r * D1 + 4 * c4] = *(const float4*)(n2 + (row0 + r) * D1 + 4 * c4);
    }
    float h3r[4];                                // h3 state in regs (lanes jg<10)
    #pragma unroll
    for (int i = 0; i < 4; ++i)
        h3r[i] = (jg < D3) ? n3[(row0 + r0 + i) * D3 + jg] : 0.f;
    __syncthreads();

    // ---------------- T synchronous Jacobi steps (2 barriers/step)
    for (int t = 0; t < TSTEPS; ++t) {
        float a1[4][4], a2[4][4], a3[4];
        #pragma unroll
        for (int i = 0; i < 4; ++i) {
            #pragma unroll
            for (int l = 0; l < 4; ++l) { a1[i][l] = c1r[i][l]; a2[i][l] = b1r[l]; }
            a3[i] = b2r;
        }

        // 2-deep software pipeline over the 32 k-chunks (A/B register buffers)
        F4 pA2[4], pA1[4], wAa[4], wAb[4], w2A;
        F4 pB2[4], pB1[4], wBa[4], wBb[4], w2B;
        LOADCH(pA2, pA1, wAa, wAb, w2A, 0);
        for (int c = 0; c < 30; c += 2) {        // 15 iterations, chunks 0..29
            LOADCH(pB2, pB1, wBa, wBb, w2B, c + 1);
            FMACH(pA2, pA1, wAa, wAb, w2A);
            LOADCH(pA2, pA1, wAa, wAb, w2A, c + 2);
            FMACH(pB2, pB1, wBa, wBb, w2B);
        }
        LOADCH(pB2, pB1, wBa, wBb, w2B, 31);     // tail: chunks 30, 31
        FMACH(pA2, pA1, wAa, wAb, w2A);
        FMACH(pB2, pB1, wBa, wBb, w2B);

        #pragma unroll
        for (int kk = 0; kk < D3; ++kk) {        // g2 += h3 @ W2 (h3 via shfl bcast)
            F4 wc; wc.v = *(const float4*)(W2 + (size_t)kk * D1 + j0);
            #pragma unroll
            for (int i = 0; i < 4; ++i) {
                float h3v = __shfl(h3r[i], kk, 32);   // lane kk of same 32-lane group
                #pragma unroll
                for (int l = 0; l < 4; ++l)
                    a2[i][l] = fmaf(h3v, wc.f[l], a2[i][l]);
            }
        }
        __syncthreads();                         // all reads of old state complete
        #pragma unroll
        for (int i = 0; i < 4; ++i) {
            *(float4*)&h1L[(r0 + i) * D1 + j0] =
                make_float4(ftanh(a1[i][0]), ftanh(a1[i][1]), ftanh(a1[i][2]), ftanh(a1[i][3]));
            *(float4*)&h2L[(r0 + i) * D1 + j0] =
                make_float4(ftanh(a2[i][0]), ftanh(a2[i][1]), ftanh(a2[i][2]), ftanh(a2[i][3]));
            h3r[i] = ftanh(a3[i]);               // garbage for jg>=10, never read
        }
        __syncthreads();                         // new state visible
    }

    // ---------------- epilogue: (h1, h2, h3) fp32, coalesced
    for (int q = tid; q < ROWS * 32; q += NT) {
        int r = q >> 5, c4 = q & 31;
        *(float4*)(out + (row0 + r) * D1 + 4 * c4)       = *(const float4*)&h1L[r * D1 + 4 * c4];
        *(float4*)(out + H2O + (row0 + r) * D1 + 4 * c4) = *(const float4*)&h2L[r * D1 + 4 * c4];
    }
    if (jg < D3) {
        #pragma unroll
        for (int i = 0; i < 4; ++i)
            out[H3O + (row0 + r0 + i) * D3 + jg] = h3r[i];
    }
}

extern "C" void kernel_launch(void* const* d_in, const int* in_sizes, int n_in,
                              void* d_out, int out_size, void* d_ws, size_t ws_size,
                              hipStream_t stream) {
    // inputs: 0:x 1:y 2:n1 3:n2 4:n3 5:W0 6:b0 7:W1 8:b1 9:W2 10:b2 11:T(=60 hard-coded)
    const float* x  = (const float*)d_in[0];
    const float* n1 = (const float*)d_in[2];
    const float* n2 = (const float*)d_in[3];
    const float* n3 = (const float*)d_in[4];
    const float* W0 = (const float*)d_in[5];
    const float* b0 = (const float*)d_in[6];
    const float* W1 = (const float*)d_in[7];
    const float* b1 = (const float*)d_in[8];
    const float* W2 = (const float*)d_in[9];
    const float* b2 = (const float*)d_in[10];

    k_fused<<<NBLK, NT, 0, stream>>>(x, n1, n2, n3, W0, b0, W1, b1, W2, b2,
                                     (float*)d_out);

    hipError_t e = hipGetLastError();
    if (e != hipSuccess) {   // surface launch error as fp32 1000+e (free on success)
        static float code[4];
        code[0] = code[1] = code[2] = code[3] = 1000.0f + (float)(int)e;
        hipMemcpyAsync(d_out, code, 4 * sizeof(float), hipMemcpyHostToDevice, stream);
    }
}

// Round 7
// 1781.960 us; speedup vs baseline: 1.0394x; 1.0394x over previous
//
#include <hip/hip_runtime.h>

// EqProp MLP relaxation (784->128->128->10, B=16384, T=60), FUSED all-FP32 kernel.
// PRECISION FINDING (prev session): W1 ~ N(0,1/128) puts the tanh relaxation at
// the edge of chaos; (I-J)^-1 amplifies bias ~260x; per-step state quantization
// accumulates. Everything stays fp32-grade.
// R6 POST-MORTEM: explicit 2-deep pipeline spilled: allocator capped VGPR at
// 128 (default 4-waves/EU budget; __launch_bounds__(512,1) does NOT raise it)
// -> ~220-reg operand pipeline went to scratch (FETCH 36MB->1.13GB = the whole
// regression). R5 model refined: 4096 ds_read_b128/step/CU ~= 41-49k cy of LDS
// pipe vs 55k measured -> ~85% LDS-instr-bound, VALU 70%. Pipeline is the
// right lever; it needs registers.
// R7: same pipeline + __attribute__((amdgpu_waves_per_eu(2,2))): real
// occupancy is 1 block/CU = 8 waves = 2/EU -> legal budget 256 VGPR. Demand
// ~212 (128 buffers + 36 acc + c1r/b1r + misc). w2r global load kept OUT of
// the prefetch set (VMEM pipe, separate vmcnt). Geometry unchanged from R5:
//   ROWS=64, NT=512 (8 waves), 4x4 thread tiles, grid=256 = 1 block/CU,
//   LDS = 64K W1 (full-period chunk swizzle) + 32K h1 + 32K h2 = 128KB.
//   Swizzle: chunk of W1[r][c] at (r<<5)|((c>>2)^(r>>2)); both GEMM read
//   patterns use the same offset co=(jg^c)<<2 and are conflict-free (R5: 8e3).
//   h1' = tanh(c1 + h2@W1)          c1 = x@W0^T+b0 in REGISTERS (loop-invariant)
//   h2' = tanh(b1 + h1@W1^T + h3@W2)   h3 state in REGISTERS (lanes jg<10,
//   h3' = tanh(b2 + h2@W2^T)           broadcast via __shfl width=32)

#define NB 16384
#define D0 784
#define D1 128
#define D3 10
#define TSTEPS 60
#define NT 512
#define ROWS 64
#define NBLK (NB / ROWS)                 // 256 blocks = 1 per CU
#define H2O ((size_t)NB * D1)
#define H3O ((size_t)2 * NB * D1)
#define XS_LD 68   // padded x-staging stride, 16B-aligned rows

__device__ __forceinline__ float ftanh(float x)
{
    // tanh(x) = 1 - 2/(exp(2x)+1); safe at +/-inf (rcp(inf)=0 -> 1; e->0 -> -1)
    float e = __expf(2.0f * x);                  // v_mul + v_exp_f32
    float r = __builtin_amdgcn_rcpf(e + 1.0f);   // v_rcp_f32, ~1 ulp
    return fmaf(-2.0f, r, 1.0f);
}

union F4 { float4 v; float f[4]; };

__global__
__attribute__((amdgpu_waves_per_eu(2, 2)))   // 2 waves/EU target -> 256-VGPR budget
__launch_bounds__(NT, 1)                     // 1 block/CU (LDS-forced anyway)
void k_fused(const float* __restrict__ x,
             const float* __restrict__ n1, const float* __restrict__ n2,
             const float* __restrict__ n3,
             const float* __restrict__ W0, const float* __restrict__ b0,
             const float* __restrict__ W1, const float* __restrict__ b1,
             const float* __restrict__ W2, const float* __restrict__ b2,
             float* __restrict__ out)
{
    __shared__ float W1L[D1 * D1];       // 64 KB, full-period chunk swizzle
    __shared__ float h1L[ROWS * D1];     // 32 KB
    __shared__ float h2L[ROWS * D1];     // 32 KB   -> total 131072 B
    float* xs = W1L;                     // x staging aliases W1L (phase 1 only)

    const int tid = threadIdx.x;
    const int jg = tid & 31, rg = tid >> 5;      // jg: col group, rg: 0..15
    const int j0 = jg * 4, r0 = rg * 4;
    const int jg3 = (jg < D3) ? jg : 0;          // clamped W2 row (a3 jg>=10 unused)
    const size_t row0 = (size_t)blockIdx.x * ROWS;

    // ---------------- phase 1: c1 = x @ W0^T + b0, kept in registers
    float c1r[4][4];
    #pragma unroll
    for (int i = 0; i < 4; ++i)
        #pragma unroll
        for (int l = 0; l < 4; ++l) c1r[i][l] = 0.f;

    for (int ch = 0; ch < 13; ++ch) {            // 784 = 12*64 + 16
        const int kb = ch * 64;
        const int klen = (ch < 12) ? 64 : 16;
        const int nv4 = klen >> 2;
        for (int q = tid; q < ROWS * nv4; q += NT) {
            int r = q / nv4, c4 = q - r * nv4;
            *(float4*)&xs[r * XS_LD + 4 * c4] =
                *(const float4*)(x + (row0 + r) * D0 + kb + 4 * c4);
        }
        __syncthreads();
        for (int k = 0; k < klen; k += 4) {
            F4 xr[4];
            #pragma unroll
            for (int i = 0; i < 4; ++i)
                xr[i].v = *(const float4*)&xs[(r0 + i) * XS_LD + k];
            #pragma unroll
            for (int l = 0; l < 4; ++l) {
                F4 w; w.v = *(const float4*)(W0 + (size_t)(j0 + l) * D0 + kb + k);
                #pragma unroll
                for (int kk = 0; kk < 4; ++kk)
                    #pragma unroll
                    for (int i = 0; i < 4; ++i)
                        c1r[i][l] = fmaf(xr[i].f[kk], w.f[kk], c1r[i][l]);
            }
        }
        __syncthreads();                 // last xs read done before W1L stage
    }
    float b1r[4];
    #pragma unroll
    for (int l = 0; l < 4; ++l) {
        float bb = b0[j0 + l];
        #pragma unroll
        for (int i = 0; i < 4; ++i) c1r[i][l] += bb;
        b1r[l] = b1[j0 + l];
    }
    const float b2r = (jg < D3) ? b2[jg] : 0.f;

    // ---------------- stage W1 into LDS (full-period swizzle) + init state
    // chunk of W1[r][c] stored at (r<<5) | ((c>>2) ^ (r>>2)); r>>2 spans 0..31.
    for (int q = tid; q < 4096; q += NT) {       // 8 float4 per thread
        int r = q >> 5, c4 = q & 31;
        int d = (r << 5) | (c4 ^ (r >> 2));
        ((float4*)W1L)[d] = ((const float4*)W1)[q];  // row-perm write: no conflict
    }
    for (int q = tid; q < ROWS * 32; q += NT) {
        int r = q >> 5, c4 = q & 31;
        *(float4*)&h1L[r * D1 + 4 * c4] = *(const float4*)(n1 + (row0 + r) * D1 + 4 * c4);
        *(float4*)&h2L[r * D1 + 4 * c4] = *(const float4*)(n2 + (row0 + r) * D1 + 4 * c4);
    }
    float h3r[4];                                // h3 state in regs (lanes jg<10)
    #pragma unroll
    for (int i = 0; i < 4; ++i)
        h3r[i] = (jg < D3) ? n3[(row0 + r0 + i) * D3 + jg] : 0.f;
    __syncthreads();

    // ---------------- T synchronous Jacobi steps (2 barriers/step)
    for (int t = 0; t < TSTEPS; ++t) {
        float a1[4][4], a2[4][4], a3[4];
        #pragma unroll
        for (int i = 0; i < 4; ++i) {
            #pragma unroll
            for (int l = 0; l < 4; ++l) { a1[i][l] = c1r[i][l]; a2[i][l] = b1r[l]; }
            a3[i] = b2r;
        }

        // load all LDS operands of chunk c_ into a named buffer set
        auto LD = [&](F4* P2, F4* P1, F4* WA, F4* WB, int c_) {
            const int k_  = c_ << 2;
            const int co_ = (jg ^ c_) << 2;
            #pragma unroll
            for (int i = 0; i < 4; ++i) {
                P2[i].v = *(const float4*)&h2L[(r0 + i) * D1 + k_];
                P1[i].v = *(const float4*)&h1L[(r0 + i) * D1 + k_];
            }
            #pragma unroll
            for (int l = 0; l < 4; ++l)
                WB[l].v = *(const float4*)&W1L[(j0 + l) * D1 + co_];
            #pragma unroll
            for (int kk = 0; kk < 4; ++kk)
                WA[kk].v = *(const float4*)&W1L[(k_ + kk) * D1 + co_];
        };
        // 144 FMAs of one chunk (w2r global load stays here: VMEM pipe)
        auto FM = [&](F4* P2, F4* P1, F4* WA, F4* WB, int c_) {
            F4 w2r; w2r.v = *(const float4*)(W2 + (size_t)jg3 * D1 + (c_ << 2));
            #pragma unroll
            for (int kk = 0; kk < 4; ++kk)
                #pragma unroll
                for (int i = 0; i < 4; ++i) {
                    #pragma unroll
                    for (int l = 0; l < 4; ++l) {
                        a1[i][l] = fmaf(P2[i].f[kk], WA[kk].f[l], a1[i][l]);
                        a2[i][l] = fmaf(P1[i].f[kk], WB[l].f[kk], a2[i][l]);
                    }
                    a3[i] = fmaf(P2[i].f[kk], w2r.f[kk], a3[i]);
                }
        };

        // 2-deep software pipeline over the 32 k-chunks (A/B register buffers)
        F4 p2A[4], p1A[4], waA[4], wbA[4];
        F4 p2B[4], p1B[4], waB[4], wbB[4];
        LD(p2A, p1A, waA, wbA, 0);
        for (int c = 0; c < 30; c += 2) {        // 15 iterations, chunks 0..29
            LD(p2B, p1B, waB, wbB, c + 1);
            FM(p2A, p1A, waA, wbA, c);
            LD(p2A, p1A, waA, wbA, c + 2);
            FM(p2B, p1B, waB, wbB, c + 1);
        }
        LD(p2B, p1B, waB, wbB, 31);              // tail: chunks 30, 31
        FM(p2A, p1A, waA, wbA, 30);
        FM(p2B, p1B, waB, wbB, 31);

        #pragma unroll
        for (int kk = 0; kk < D3; ++kk) {        // g2 += h3 @ W2 (h3 via shfl bcast)
            F4 wc; wc.v = *(const float4*)(W2 + (size_t)kk * D1 + j0);
            #pragma unroll
            for (int i = 0; i < 4; ++i) {
                float h3v = __shfl(h3r[i], kk, 32);   // lane kk of same 32-lane group
                #pragma unroll
                for (int l = 0; l < 4; ++l)
                    a2[i][l] = fmaf(h3v, wc.f[l], a2[i][l]);
            }
        }
        __syncthreads();                         // all reads of old state complete
        #pragma unroll
        for (int i = 0; i < 4; ++i) {
            *(float4*)&h1L[(r0 + i) * D1 + j0] =
                make_float4(ftanh(a1[i][0]), ftanh(a1[i][1]), ftanh(a1[i][2]), ftanh(a1[i][3]));
            *(float4*)&h2L[(r0 + i) * D1 + j0] =
                make_float4(ftanh(a2[i][0]), ftanh(a2[i][1]), ftanh(a2[i][2]), ftanh(a2[i][3]));
            h3r[i] = ftanh(a3[i]);               // garbage for jg>=10, never read
        }
        __syncthreads();                         // new state visible
    }

    // ---------------- epilogue: (h1, h2, h3) fp32, coalesced
    for (int q = tid; q < ROWS * 32; q += NT) {
        int r = q >> 5, c4 = q & 31;
        *(float4*)(out + (row0 + r) * D1 + 4 * c4)       = *(const float4*)&h1L[r * D1 + 4 * c4];
        *(float4*)(out + H2O + (row0 + r) * D1 + 4 * c4) = *(const float4*)&h2L[r * D1 + 4 * c4];
    }
    if (jg < D3) {
        #pragma unroll
        for (int i = 0; i < 4; ++i)
            out[H3O + (row0 + r0 + i) * D3 + jg] = h3r[i];
    }
}

extern "C" void kernel_launch(void* const* d_in, const int* in_sizes, int n_in,
                              void* d_out, int out_size, void* d_ws, size_t ws_size,
                              hipStream_t stream) {
    // inputs: 0:x 1:y 2:n1 3:n2 4:n3 5:W0 6:b0 7:W1 8:b1 9:W2 10:b2 11:T(=60 hard-coded)
    const float* x  = (const float*)d_in[0];
    const float* n1 = (const float*)d_in[2];
    const float* n2 = (const float*)d_in[3];
    const float* n3 = (const float*)d_in[4];
    const float* W0 = (const float*)d_in[5];
    const float* b0 = (const float*)d_in[6];
    const float* W1 = (const float*)d_in[7];
    const float* b1 = (const float*)d_in[8];
    const float* W2 = (const float*)d_in[9];
    const float* b2 = (const float*)d_in[10];

    k_fused<<<NBLK, NT, 0, stream>>>(x, n1, n2, n3, W0, b0, W1, b1, W2, b2,
                                     (float*)d_out);

    hipError_t e = hipGetLastError();
    if (e != hipSuccess) {   // surface launch error as fp32 1000+e (free on success)
        static float code[4];
        code[0] = code[1] = code[2] = code[3] = 1000.0f + (float)(int)e;
        hipMemcpyAsync(d_out, code, 4 * sizeof(float), hipMemcpyHostToDevice, stream);
    }
}

// Round 8
// 1595.291 us; speedup vs baseline: 1.1610x; 1.1170x over previous
//
#include <hip/hip_runtime.h>

// EqProp MLP relaxation (784->128->128->10, B=16384, T=60), FUSED all-FP32 kernel.
// PRECISION FINDING (prev session): W1 ~ N(0,1/128) -> edge of chaos; errors
// amplified ~260x; everything stays fp32-grade.
// R6/R7 POST-MORTEM: 8-wave blocks (__launch_bounds__(512,1), with or without
// amdgpu_waves_per_eu(2,2)) are HARD-CAPPED at 128 VGPR by the backend ->
// any 2-deep pipeline (~200+ regs) spills (FETCH 36MB->650MB-1.1GB). But the
// 4-wave NT=256 / bounds(256,1) shape was allowed 132 VGPR, no spill (R3).
// R8: redesign around NT=256, which ALSO lowers the structural LDS floor:
//   per-CU per-step ds_read_b128 = state(rows/thread x waves = const 2048)
//   + weights(prop. waves: 1024)  -> 3072 vs R5's 4096  (~37k cy ~ 920us floor)
//   * ROWS=64, R=8 rows x 4 cols per thread, 4 waves, grid=256 = 1 block/CU
//   * LDS: W1 64K (full-period swizzle, R5-proven conflict-free) + h1 32K +
//     h2 32K + c1 32K = exactly 163840 B (R3-proven launchable)
//   * c1 = x@W0^T+b0 computed once into LDS (frees 32 regs for the pipeline)
//   * 2-deep register pipeline (state+weights+W2 row, ~200 buffer regs) hides
//     LDS/VMEM latency at 1 wave/SIMD; budget 512 regs, no spill up to ~450
//   h1' = tanh(c1 + h2@W1)
//   h2' = tanh(b1 + h1@W1^T + h3@W2)   h3 state in REGISTERS (lanes jg<10,
//   h3' = tanh(b2 + h2@W2^T)           broadcast via __shfl width=32)

#define NB 16384
#define D0 784
#define D1 128
#define D3 10
#define TSTEPS 60
#define NT 256
#define ROWS 64
#define R 8                              // rows per thread
#define NBLK (NB / ROWS)                 // 256 blocks = 1 per CU
#define H2O ((size_t)NB * D1)
#define H3O ((size_t)2 * NB * D1)
#define XS_LD 68   // padded x-staging stride, 16B-aligned rows

__device__ __forceinline__ float ftanh(float x)
{
    // tanh(x) = 1 - 2/(exp(2x)+1); safe at +/-inf (rcp(inf)=0 -> 1; e->0 -> -1)
    float e = __expf(2.0f * x);                  // v_mul + v_exp_f32
    float r = __builtin_amdgcn_rcpf(e + 1.0f);   // v_rcp_f32, ~1 ulp
    return fmaf(-2.0f, r, 1.0f);
}

union F4 { float4 v; float f[4]; };

__global__
__attribute__((amdgpu_waves_per_eu(1)))      // min 1 wave/EU: full 512-reg budget
__launch_bounds__(NT, 1)                     // 4-wave shape: allocator >128 OK (R3)
void k_fused(const float* __restrict__ x,
             const float* __restrict__ n1, const float* __restrict__ n2,
             const float* __restrict__ n3,
             const float* __restrict__ W0, const float* __restrict__ b0,
             const float* __restrict__ W1, const float* __restrict__ b1,
             const float* __restrict__ W2, const float* __restrict__ b2,
             float* __restrict__ out)
{
    __shared__ float W1L[D1 * D1];       // 64 KB, full-period chunk swizzle
    __shared__ float h1L[ROWS * D1];     // 32 KB
    __shared__ float h2L[ROWS * D1];     // 32 KB
    __shared__ float c1L[ROWS * D1];     // 32 KB  -> total exactly 163840 B
    float* xs = W1L;                     // x staging aliases W1L (phase 1 only)

    const int tid = threadIdx.x;
    const int jg = tid & 31, rg = tid >> 5;      // jg: col group, rg: 0..7
    const int j0 = jg * 4, r0 = rg * R;
    const int jg3 = (jg < D3) ? jg : 0;          // clamped W2 row (a3 jg>=10 unused)
    const size_t row0 = (size_t)blockIdx.x * ROWS;

    // ---------------- phase 1: c1 = x @ W0^T + b0 -> c1L (regs only transient)
    {
        float c1r[R][4];
        #pragma unroll
        for (int i = 0; i < R; ++i)
            #pragma unroll
            for (int l = 0; l < 4; ++l) c1r[i][l] = 0.f;

        for (int ch = 0; ch < 13; ++ch) {        // 784 = 12*64 + 16
            const int kb = ch * 64;
            const int klen = (ch < 12) ? 64 : 16;
            const int nv4 = klen >> 2;
            for (int q = tid; q < ROWS * nv4; q += NT) {
                int r = q / nv4, c4 = q - r * nv4;
                *(float4*)&xs[r * XS_LD + 4 * c4] =
                    *(const float4*)(x + (row0 + r) * D0 + kb + 4 * c4);
            }
            __syncthreads();
            for (int k = 0; k < klen; k += 4) {
                F4 xr[R];
                #pragma unroll
                for (int i = 0; i < R; ++i)
                    xr[i].v = *(const float4*)&xs[(r0 + i) * XS_LD + k];
                #pragma unroll
                for (int l = 0; l < 4; ++l) {
                    F4 w; w.v = *(const float4*)(W0 + (size_t)(j0 + l) * D0 + kb + k);
                    #pragma unroll
                    for (int kk = 0; kk < 4; ++kk)
                        #pragma unroll
                        for (int i = 0; i < R; ++i)
                            c1r[i][l] = fmaf(xr[i].f[kk], w.f[kk], c1r[i][l]);
                }
            }
            __syncthreads();             // last xs read done before next stage/W1L
        }
        #pragma unroll
        for (int i = 0; i < R; ++i) {
            F4 cv;
            #pragma unroll
            for (int l = 0; l < 4; ++l) cv.f[l] = c1r[i][l] + b0[j0 + l];
            *(float4*)&c1L[(r0 + i) * D1 + j0] = cv.v;   // conflict-free spread
        }
    }
    float b1r[4];
    #pragma unroll
    for (int l = 0; l < 4; ++l) b1r[l] = b1[j0 + l];
    const float b2r = (jg < D3) ? b2[jg] : 0.f;

    // ---------------- stage W1 into LDS (full-period swizzle) + init state
    // chunk of W1[r][c] stored at (r<<5) | ((c>>2) ^ (r>>2)); r>>2 spans 0..31.
    for (int q = tid; q < 4096; q += NT) {       // 16 float4 per thread
        int r = q >> 5, c4 = q & 31;
        int d = (r << 5) | (c4 ^ (r >> 2));
        ((float4*)W1L)[d] = ((const float4*)W1)[q];  // row-perm write: no conflict
    }
    for (int q = tid; q < ROWS * 32; q += NT) {
        int r = q >> 5, c4 = q & 31;
        *(float4*)&h1L[r * D1 + 4 * c4] = *(const float4*)(n1 + (row0 + r) * D1 + 4 * c4);
        *(float4*)&h2L[r * D1 + 4 * c4] = *(const float4*)(n2 + (row0 + r) * D1 + 4 * c4);
    }
    float h3r[R];                                // h3 state in regs (lanes jg<10)
    #pragma unroll
    for (int i = 0; i < R; ++i)
        h3r[i] = (jg < D3) ? n3[(row0 + r0 + i) * D3 + jg] : 0.f;
    __syncthreads();

    // ---------------- T synchronous Jacobi steps (2 barriers/step)
    for (int t = 0; t < TSTEPS; ++t) {
        float a1[R][4], a2[R][4], a3[R];
        #pragma unroll
        for (int i = 0; i < R; ++i) {
            F4 cv; cv.v = *(const float4*)&c1L[(r0 + i) * D1 + j0];
            #pragma unroll
            for (int l = 0; l < 4; ++l) { a1[i][l] = cv.f[l]; a2[i][l] = b1r[l]; }
            a3[i] = b2r;
        }

        // load all operands of chunk c_ into a named register buffer set
        auto LD = [&](F4* P2, F4* P1, F4* WA, F4* WB, F4& W2R, int c_) {
            const int k_  = c_ << 2;
            const int co_ = (jg ^ c_) << 2;
            #pragma unroll
            for (int i = 0; i < R; ++i) {
                P2[i].v = *(const float4*)&h2L[(r0 + i) * D1 + k_];  // 2-addr bcast
                P1[i].v = *(const float4*)&h1L[(r0 + i) * D1 + k_];
            }
            #pragma unroll
            for (int l = 0; l < 4; ++l)
                WB[l].v = *(const float4*)&W1L[(j0 + l) * D1 + co_]; // 0-conflict
            #pragma unroll
            for (int kk = 0; kk < 4; ++kk)
                WA[kk].v = *(const float4*)&W1L[(k_ + kk) * D1 + co_];
            W2R.v = *(const float4*)(W2 + (size_t)jg3 * D1 + k_);    // VMEM, L1-hot
        };
        // 288 FMAs of one chunk
        auto FM = [&](F4* P2, F4* P1, F4* WA, F4* WB, F4& W2R) {
            #pragma unroll
            for (int kk = 0; kk < 4; ++kk)
                #pragma unroll
                for (int i = 0; i < R; ++i) {
                    #pragma unroll
                    for (int l = 0; l < 4; ++l) {
                        a1[i][l] = fmaf(P2[i].f[kk], WA[kk].f[l], a1[i][l]);
                        a2[i][l] = fmaf(P1[i].f[kk], WB[l].f[kk], a2[i][l]);
                    }
                    a3[i] = fmaf(P2[i].f[kk], W2R.f[kk], a3[i]);
                }
        };

        // 2-deep software pipeline over the 32 k-chunks (A/B register buffers)
        F4 p2A[R], p1A[R], waA[4], wbA[4], w2A;
        F4 p2B[R], p1B[R], waB[4], wbB[4], w2B;
        LD(p2A, p1A, waA, wbA, w2A, 0);
        for (int c = 0; c < 30; c += 2) {        // 15 iterations, chunks 0..29
            LD(p2B, p1B, waB, wbB, w2B, c + 1);
            FM(p2A, p1A, waA, wbA, w2A);
            LD(p2A, p1A, waA, wbA, w2A, c + 2);
            FM(p2B, p1B, waB, wbB, w2B);
        }
        LD(p2B, p1B, waB, wbB, w2B, 31);         // tail: chunks 30, 31
        FM(p2A, p1A, waA, wbA, w2A);
        FM(p2B, p1B, waB, wbB, w2B);

        #pragma unroll
        for (int kk = 0; kk < D3; ++kk) {        // g2 += h3 @ W2 (h3 via shfl bcast)
            F4 wc; wc.v = *(const float4*)(W2 + (size_t)kk * D1 + j0);
            #pragma unroll
            for (int i = 0; i < R; ++i) {
                float h3v = __shfl(h3r[i], kk, 32);   // lane kk of same 32-lane group
                #pragma unroll
                for (int l = 0; l < 4; ++l)
                    a2[i][l] = fmaf(h3v, wc.f[l], a2[i][l]);
            }
        }
        __syncthreads();                         // all reads of old state complete
        #pragma unroll
        for (int i = 0; i < R; ++i) {
            *(float4*)&h1L[(r0 + i) * D1 + j0] =
                make_float4(ftanh(a1[i][0]), ftanh(a1[i][1]), ftanh(a1[i][2]), ftanh(a1[i][3]));
            *(float4*)&h2L[(r0 + i) * D1 + j0] =
                make_float4(ftanh(a2[i][0]), ftanh(a2[i][1]), ftanh(a2[i][2]), ftanh(a2[i][3]));
            h3r[i] = ftanh(a3[i]);               // garbage for jg>=10, never read
        }
        __syncthreads();                         // new state visible
    }

    // ---------------- epilogue: (h1, h2, h3) fp32, coalesced
    for (int q = tid; q < ROWS * 32; q += NT) {
        int r = q >> 5, c4 = q & 31;
        *(float4*)(out + (row0 + r) * D1 + 4 * c4)       = *(const float4*)&h1L[r * D1 + 4 * c4];
        *(float4*)(out + H2O + (row0 + r) * D1 + 4 * c4) = *(const float4*)&h2L[r * D1 + 4 * c4];
    }
    if (jg < D3) {
        #pragma unroll
        for (int i = 0; i < R; ++i)
            out[H3O + (row0 + r0 + i) * D3 + jg] = h3r[i];
    }
}

extern "C" void kernel_launch(void* const* d_in, const int* in_sizes, int n_in,
                              void* d_out, int out_size, void* d_ws, size_t ws_size,
                              hipStream_t stream) {
    // inputs: 0:x 1:y 2:n1 3:n2 4:n3 5:W0 6:b0 7:W1 8:b1 9:W2 10:b2 11:T(=60 hard-coded)
    const float* x  = (const float*)d_in[0];
    const float* n1 = (const float*)d_in[2];
    const float* n2 = (const float*)d_in[3];
    const float* n3 = (const float*)d_in[4];
    const float* W0 = (const float*)d_in[5];
    const float* b0 = (const float*)d_in[6];
    const float* W1 = (const float*)d_in[7];
    const float* b1 = (const float*)d_in[8];
    const float* W2 = (const float*)d_in[9];
    const float* b2 = (const float*)d_in[10];

    k_fused<<<NBLK, NT, 0, stream>>>(x, n1, n2, n3, W0, b0, W1, b1, W2, b2,
                                     (float*)d_out);

    hipError_t e = hipGetLastError();
    if (e != hipSuccess) {   // surface launch error as fp32 1000+e (free on success)
        static float code[4];
        code[0] = code[1] = code[2] = code[3] = 1000.0f + (float)(int)e;
        hipMemcpyAsync(d_out, code, 4 * sizeof(float), hipMemcpyHostToDevice, stream);
    }
}

// Round 9
// 1300.824 us; speedup vs baseline: 1.4238x; 1.2264x over previous
//
#include <hip/hip_runtime.h>

// EqProp MLP relaxation (784->128->128->10, B=16384, T=60), FUSED all-FP32 kernel.
// PRECISION FINDING (prev session): W1 ~ N(0,1/128) -> edge of chaos; errors
// amplified ~260x; everything stays fp32-grade.
// R8 POST-MORTEM: pipeline got regs (208, no spill) but 1 wave/SIMD lost to
// R5's 2 waves/SIMD (eff. 20.8 vs 13.5 cy/ds_read: lockstep waves burst+starve
// the LDS pipe). Empirical law: need 2 waves/SIMD AND R=8 weight economy AND
// <=128 VGPR (hard cap for 512-thread blocks). One thread doing g1+g2 at R=8
// needs ~200 regs -> impossible. R9: WAVE SPECIALIZATION halves the demand:
//   waves 0-3 (task A): h1' = tanh(c1 + h2@W1), h3' = tanh(b2 + h2@W2^T)
//   waves 4-7 (task B): h2' = tanh(b1 + h1@W1^T + h3@W2)
// Each task: R=8 rows x 4 cols, 12 b128/chunk (8 broadcast state + 4 weight),
// ~110 VGPR. Per CU/step: 3072 reads (R8 economy) at 2 waves/SIMD (R5
// concurrency); VALU ~= LDS ~= 640 cy/chunk, balanced.
// LDS: W1 64K (full-period swizzle: chunk of W1[r][c] at (r<<5)|((c>>2)^(r>>2));
// both read patterns use co=(jg^c)<<2, conflict-free per R5) + h1 32K + h2 32K
// + c1 32K = 163840 B exactly. h3 exchanges A->B through out's H3O region
// (same block/CU; __syncthreads orders global within block; L2-hot; final step
// leaves correct values -> no epilogue h3 write). Accumulation order per
// output identical to R8 -> expect bit-identical absmax.

#define NB 16384
#define D0 784
#define D1 128
#define D3 10
#define TSTEPS 60
#define NT 512
#define ROWS 64
#define R 8                              // rows per thread within a task
#define NBLK (NB / ROWS)                 // 256 blocks = 1 per CU
#define H2O ((size_t)NB * D1)
#define H3O ((size_t)2 * NB * D1)
#define XS_LD 68   // padded x-staging stride, 16B-aligned rows

__device__ __forceinline__ float ftanh(float x)
{
    // tanh(x) = 1 - 2/(exp(2x)+1); safe at +/-inf (rcp(inf)=0 -> 1; e->0 -> -1)
    float e = __expf(2.0f * x);                  // v_mul + v_exp_f32
    float r = __builtin_amdgcn_rcpf(e + 1.0f);   // v_rcp_f32, ~1 ulp
    return fmaf(-2.0f, r, 1.0f);
}

union F4 { float4 v; float f[4]; };

__global__ __launch_bounds__(NT, 1)
void k_fused(const float* __restrict__ x,
             const float* __restrict__ n1, const float* __restrict__ n2,
             const float* __restrict__ n3,
             const float* __restrict__ W0, const float* __restrict__ b0,
             const float* __restrict__ W1, const float* __restrict__ b1,
             const float* __restrict__ W2, const float* __restrict__ b2,
             float* __restrict__ out)
{
    __shared__ float W1L[D1 * D1];       // 64 KB, full-period chunk swizzle
    __shared__ float h1L[ROWS * D1];     // 32 KB
    __shared__ float h2L[ROWS * D1];     // 32 KB
    __shared__ float c1L[ROWS * D1];     // 32 KB  -> total exactly 163840 B
    float* xs = W1L;                     // x staging aliases W1L (phase 1 only)

    const int tid = threadIdx.x;
    const int jg = tid & 31;             // col group (j0 = 4*jg)
    const int j0 = jg * 4;
    const int jg3 = (jg < D3) ? jg : 0;  // clamped W2 row (a3 of jg>=10 unused)
    const size_t row0 = (size_t)blockIdx.x * ROWS;

    // ---------------- phase 1: c1 = x @ W0^T + b0 -> c1L (all 512 threads)
    {
        const int rgp = tid >> 5;        // 0..15, 4 rows each
        const int rp0 = rgp * 4;
        float c1r[4][4];
        #pragma unroll
        for (int i = 0; i < 4; ++i)
            #pragma unroll
            for (int l = 0; l < 4; ++l) c1r[i][l] = 0.f;

        for (int ch = 0; ch < 13; ++ch) {        // 784 = 12*64 + 16
            const int kb = ch * 64;
            const int klen = (ch < 12) ? 64 : 16;
            const int nv4 = klen >> 2;
            for (int q = tid; q < ROWS * nv4; q += NT) {
                int r = q / nv4, c4 = q - r * nv4;
                *(float4*)&xs[r * XS_LD + 4 * c4] =
                    *(const float4*)(x + (row0 + r) * D0 + kb + 4 * c4);
            }
            __syncthreads();
            for (int k = 0; k < klen; k += 4) {
                F4 xr[4];
                #pragma unroll
                for (int i = 0; i < 4; ++i)
                    xr[i].v = *(const float4*)&xs[(rp0 + i) * XS_LD + k];
                #pragma unroll
                for (int l = 0; l < 4; ++l) {
                    F4 w; w.v = *(const float4*)(W0 + (size_t)(j0 + l) * D0 + kb + k);
                    #pragma unroll
                    for (int kk = 0; kk < 4; ++kk)
                        #pragma unroll
                        for (int i = 0; i < 4; ++i)
                            c1r[i][l] = fmaf(xr[i].f[kk], w.f[kk], c1r[i][l]);
                }
            }
            __syncthreads();             // last xs read done before W1L stage
        }
        #pragma unroll
        for (int i = 0; i < 4; ++i) {
            F4 cv;
            #pragma unroll
            for (int l = 0; l < 4; ++l) cv.f[l] = c1r[i][l] + b0[j0 + l];
            *(float4*)&c1L[(rp0 + i) * D1 + j0] = cv.v;
        }
    }

    // ---------------- stage W1 (swizzled) + init state + n3 -> out exchange
    for (int q = tid; q < 4096; q += NT) {       // 8 float4 per thread
        int r = q >> 5, c4 = q & 31;
        int d = (r << 5) | (c4 ^ (r >> 2));
        ((float4*)W1L)[d] = ((const float4*)W1)[q];  // row-perm write: no conflict
    }
    for (int q = tid; q < ROWS * 32; q += NT) {
        int r = q >> 5, c4 = q & 31;
        *(float4*)&h1L[r * D1 + 4 * c4] = *(const float4*)(n1 + (row0 + r) * D1 + 4 * c4);
        *(float4*)&h2L[r * D1 + 4 * c4] = *(const float4*)(n2 + (row0 + r) * D1 + 4 * c4);
    }
    for (int q = tid; q < ROWS * D3; q += NT)    // h3 state lives in out[H3O..]
        out[H3O + (row0 + q / D3) * D3 + (q % D3)] = n3[(row0 + q / D3) * D3 + (q % D3)];
    __syncthreads();

    // ---------------- T Jacobi steps: wave-specialized, 2 barriers/step
    const int rga = (tid >> 5) & 7;      // 8 row-groups per task
    const int r0 = rga * R;
    const bool taskA = (tid < 256);
    float b1r[4];
    #pragma unroll
    for (int l = 0; l < 4; ++l) b1r[l] = b1[j0 + l];
    const float b2r = (jg < D3) ? b2[jg] : 0.f;

    for (int t = 0; t < TSTEPS; ++t) {
        float acc[R][4];                 // a1 (task A) or a2 (task B)
        float a3[R];
        if (taskA) {
            // ---- task A: a1 = c1 + h2@W1 ; a3 = b2 + h2@W2^T
            #pragma unroll
            for (int i = 0; i < R; ++i) {
                F4 cv; cv.v = *(const float4*)&c1L[(r0 + i) * D1 + j0];
                #pragma unroll
                for (int l = 0; l < 4; ++l) acc[i][l] = cv.f[l];
                a3[i] = b2r;
            }
            for (int c = 0; c < 32; ++c) {
                const int k = c << 2, co = (jg ^ c) << 2;
                F4 wa[4], p2[R], w2r;
                #pragma unroll
                for (int kk = 0; kk < 4; ++kk)           // g1 row read, perm'd
                    wa[kk].v = *(const float4*)&W1L[(k + kk) * D1 + co];
                #pragma unroll
                for (int i = 0; i < R; ++i)              // 2-addr broadcast
                    p2[i].v = *(const float4*)&h2L[(r0 + i) * D1 + k];
                w2r.v = *(const float4*)(W2 + (size_t)jg3 * D1 + k);  // L1-hot
                #pragma unroll
                for (int kk = 0; kk < 4; ++kk)
                    #pragma unroll
                    for (int i = 0; i < R; ++i) {
                        #pragma unroll
                        for (int l = 0; l < 4; ++l)
                            acc[i][l] = fmaf(p2[i].f[kk], wa[kk].f[l], acc[i][l]);
                        a3[i] = fmaf(p2[i].f[kk], w2r.f[kk], a3[i]);
                    }
            }
        } else {
            // ---- task B: a2 = b1 + h1@W1^T + h3@W2
            #pragma unroll
            for (int i = 0; i < R; ++i)
                #pragma unroll
                for (int l = 0; l < 4; ++l) acc[i][l] = b1r[l];
            for (int c = 0; c < 32; ++c) {
                const int k = c << 2, co = (jg ^ c) << 2;
                F4 wb[4], p1[R];
                #pragma unroll
                for (int l = 0; l < 4; ++l)              // g2 col-slice, 0-conflict
                    wb[l].v = *(const float4*)&W1L[(j0 + l) * D1 + co];
                #pragma unroll
                for (int i = 0; i < R; ++i)
                    p1[i].v = *(const float4*)&h1L[(r0 + i) * D1 + k];
                #pragma unroll
                for (int kk = 0; kk < 4; ++kk)
                    #pragma unroll
                    for (int i = 0; i < R; ++i)
                        #pragma unroll
                        for (int l = 0; l < 4; ++l)
                            acc[i][l] = fmaf(p1[i].f[kk], wb[l].f[kk], acc[i][l]);
            }
            for (int kk = 0; kk < D3; ++kk) {            // + h3_old @ W2
                F4 wc; wc.v = *(const float4*)(W2 + (size_t)kk * D1 + j0);
                #pragma unroll
                for (int i = 0; i < R; ++i) {
                    float h3v = out[H3O + (row0 + r0 + i) * D3 + kk];  // bcast L1 hit
                    #pragma unroll
                    for (int l = 0; l < 4; ++l)
                        acc[i][l] = fmaf(h3v, wc.f[l], acc[i][l]);
                }
            }
        }
        __syncthreads();                 // all reads of old state complete
        if (taskA) {
            #pragma unroll
            for (int i = 0; i < R; ++i)
                *(float4*)&h1L[(r0 + i) * D1 + j0] =
                    make_float4(ftanh(acc[i][0]), ftanh(acc[i][1]),
                                ftanh(acc[i][2]), ftanh(acc[i][3]));
            if (jg < D3) {
                #pragma unroll
                for (int i = 0; i < R; ++i)
                    out[H3O + (row0 + r0 + i) * D3 + jg] = ftanh(a3[i]);
            }
        } else {
            #pragma unroll
            for (int i = 0; i < R; ++i)
                *(float4*)&h2L[(r0 + i) * D1 + j0] =
                    make_float4(ftanh(acc[i][0]), ftanh(acc[i][1]),
                                ftanh(acc[i][2]), ftanh(acc[i][3]));
        }
        __syncthreads();                 // new state (incl. out-h3) visible
    }

    // ---------------- epilogue: h1, h2 (h3 already final in out[H3O..])
    for (int q = tid; q < ROWS * 32; q += NT) {
        int r = q >> 5, c4 = q & 31;
        *(float4*)(out + (row0 + r) * D1 + 4 * c4)       = *(const float4*)&h1L[r * D1 + 4 * c4];
        *(float4*)(out + H2O + (row0 + r) * D1 + 4 * c4) = *(const float4*)&h2L[r * D1 + 4 * c4];
    }
}

extern "C" void kernel_launch(void* const* d_in, const int* in_sizes, int n_in,
                              void* d_out, int out_size, void* d_ws, size_t ws_size,
                              hipStream_t stream) {
    // inputs: 0:x 1:y 2:n1 3:n2 4:n3 5:W0 6:b0 7:W1 8:b1 9:W2 10:b2 11:T(=60 hard-coded)
    const float* x  = (const float*)d_in[0];
    const float* n1 = (const float*)d_in[2];
    const float* n2 = (const float*)d_in[3];
    const float* n3 = (const float*)d_in[4];
    const float* W0 = (const float*)d_in[5];
    const float* b0 = (const float*)d_in[6];
    const float* W1 = (const float*)d_in[7];
    const float* b1 = (const float*)d_in[8];
    const float* W2 = (const float*)d_in[9];
    const float* b2 = (const float*)d_in[10];

    k_fused<<<NBLK, NT, 0, stream>>>(x, n1, n2, n3, W0, b0, W1, b1, W2, b2,
                                     (float*)d_out);

    hipError_t e = hipGetLastError();
    if (e != hipSuccess) {   // surface launch error as fp32 1000+e (free on success)
        static float code[4];
        code[0] = code[1] = code[2] = code[3] = 1000.0f + (float)(int)e;
        hipMemcpyAsync(d_out, code, 4 * sizeof(float), hipMemcpyHostToDevice, stream);
    }
}

// Round 10
// 1266.339 us; speedup vs baseline: 1.4626x; 1.0272x over previous
//
#include <hip/hip_runtime.h>

// EqProp MLP relaxation (784->128->128->10, B=16384, T=60), FUSED all-FP32 kernel.
// PRECISION FINDING (prev session): W1 ~ N(0,1/128) -> edge of chaos; errors
// amplified ~260x; everything stays fp32-grade.
// R9 (1301us, best): wave specialization. waves 0-3 task A (h1'+h3', read h2),
// waves 4-7 task B (h2', read h1+h3). 104 VGPR < 128 cap, 2 waves/SIMD,
// 3072 ds_read_b128/step/CU, conflicts nil. Remaining slack: per-chunk
// {12 reads -> lgkm wait -> 160 dependent FMA} leaves VALU 69% busy; address
// arith ~25 VALU/chunk.
// R10: (a) depth-1 WEIGHT pipeline per task (+16 regs, X/Y static rotation):
// chunk c+1's spread weight reads issue before chunk c's FMAs -> counted
// lgkmcnt waits hide weight latency under 320 cy FMA. State reads stay
// just-in-time (2-addr broadcasts, cheap). (b) chunk-PAIR loop (cp<16) with
// pointer increments -> state/weight row offsets become base+immediate,
// cutting addr VALU ~25 -> ~6 per chunk. Math order unchanged (absmax should
// be bit-identical). Geometry unchanged from R9:
//   NT=512, ROWS=64, R=8 rows x 4 cols per task thread, grid=256 = 1 blk/CU,
//   LDS: W1 64K full-period swizzle (chunk of W1[r][c] at (r<<5)|((c>>2)^(r>>2)),
//   both patterns read co=(jg^c)<<2, conflict-free) + h1 32K + h2 32K + c1 32K
//   = 163840 B. h3 exchanges A->B through out[H3O] (same block/CU, L2-hot).

#define NB 16384
#define D0 784
#define D1 128
#define D3 10
#define TSTEPS 60
#define NT 512
#define ROWS 64
#define R 8                              // rows per thread within a task
#define NBLK (NB / ROWS)                 // 256 blocks = 1 per CU
#define H2O ((size_t)NB * D1)
#define H3O ((size_t)2 * NB * D1)
#define XS_LD 68   // padded x-staging stride, 16B-aligned rows

__device__ __forceinline__ float ftanh(float x)
{
    // tanh(x) = 1 - 2/(exp(2x)+1); safe at +/-inf (rcp(inf)=0 -> 1; e->0 -> -1)
    float e = __expf(2.0f * x);                  // v_mul + v_exp_f32
    float r = __builtin_amdgcn_rcpf(e + 1.0f);   // v_rcp_f32, ~1 ulp
    return fmaf(-2.0f, r, 1.0f);
}

union F4 { float4 v; float f[4]; };

__global__ __launch_bounds__(NT, 1)
void k_fused(const float* __restrict__ x,
             const float* __restrict__ n1, const float* __restrict__ n2,
             const float* __restrict__ n3,
             const float* __restrict__ W0, const float* __restrict__ b0,
             const float* __restrict__ W1, const float* __restrict__ b1,
             const float* __restrict__ W2, const float* __restrict__ b2,
             float* __restrict__ out)
{
    __shared__ float W1L[D1 * D1];       // 64 KB, full-period chunk swizzle
    __shared__ float h1L[ROWS * D1];     // 32 KB
    __shared__ float h2L[ROWS * D1];     // 32 KB
    __shared__ float c1L[ROWS * D1];     // 32 KB  -> total exactly 163840 B
    float* xs = W1L;                     // x staging aliases W1L (phase 1 only)

    const int tid = threadIdx.x;
    const int jg = tid & 31;             // col group (j0 = 4*jg)
    const int j0 = jg * 4;
    const int jg3 = (jg < D3) ? jg : 0;  // clamped W2 row (a3 of jg>=10 unused)
    const size_t row0 = (size_t)blockIdx.x * ROWS;

    // ---------------- phase 1: c1 = x @ W0^T + b0 -> c1L (all 512 threads)
    {
        const int rgp = tid >> 5;        // 0..15, 4 rows each
        const int rp0 = rgp * 4;
        float c1r[4][4];
        #pragma unroll
        for (int i = 0; i < 4; ++i)
            #pragma unroll
            for (int l = 0; l < 4; ++l) c1r[i][l] = 0.f;

        for (int ch = 0; ch < 13; ++ch) {        // 784 = 12*64 + 16
            const int kb = ch * 64;
            const int klen = (ch < 12) ? 64 : 16;
            const int nv4 = klen >> 2;
            for (int q = tid; q < ROWS * nv4; q += NT) {
                int r = q / nv4, c4 = q - r * nv4;
                *(float4*)&xs[r * XS_LD + 4 * c4] =
                    *(const float4*)(x + (row0 + r) * D0 + kb + 4 * c4);
            }
            __syncthreads();
            for (int k = 0; k < klen; k += 4) {
                F4 xr[4];
                #pragma unroll
                for (int i = 0; i < 4; ++i)
                    xr[i].v = *(const float4*)&xs[(rp0 + i) * XS_LD + k];
                #pragma unroll
                for (int l = 0; l < 4; ++l) {
                    F4 w; w.v = *(const float4*)(W0 + (size_t)(j0 + l) * D0 + kb + k);
                    #pragma unroll
                    for (int kk = 0; kk < 4; ++kk)
                        #pragma unroll
                        for (int i = 0; i < 4; ++i)
                            c1r[i][l] = fmaf(xr[i].f[kk], w.f[kk], c1r[i][l]);
                }
            }
            __syncthreads();             // last xs read done before W1L stage
        }
        #pragma unroll
        for (int i = 0; i < 4; ++i) {
            F4 cv;
            #pragma unroll
            for (int l = 0; l < 4; ++l) cv.f[l] = c1r[i][l] + b0[j0 + l];
            *(float4*)&c1L[(rp0 + i) * D1 + j0] = cv.v;
        }
    }

    // ---------------- stage W1 (swizzled) + init state + n3 -> out exchange
    for (int q = tid; q < 4096; q += NT) {       // 8 float4 per thread
        int r = q >> 5, c4 = q & 31;
        int d = (r << 5) | (c4 ^ (r >> 2));
        ((float4*)W1L)[d] = ((const float4*)W1)[q];  // row-perm write: no conflict
    }
    for (int q = tid; q < ROWS * 32; q += NT) {
        int r = q >> 5, c4 = q & 31;
        *(float4*)&h1L[r * D1 + 4 * c4] = *(const float4*)(n1 + (row0 + r) * D1 + 4 * c4);
        *(float4*)&h2L[r * D1 + 4 * c4] = *(const float4*)(n2 + (row0 + r) * D1 + 4 * c4);
    }
    for (int q = tid; q < ROWS * D3; q += NT)    // h3 state lives in out[H3O..]
        out[H3O + (row0 + q / D3) * D3 + (q % D3)] = n3[(row0 + q / D3) * D3 + (q % D3)];
    __syncthreads();

    // ---------------- T Jacobi steps: wave-specialized, 2 barriers/step
    const int rga = (tid >> 5) & 7;      // 8 row-groups per task
    const int r0 = rga * R;
    const bool taskA = (tid < 256);
    float b1r[4];
    #pragma unroll
    for (int l = 0; l < 4; ++l) b1r[l] = b1[j0 + l];
    const float b2r = (jg < D3) ? b2[jg] : 0.f;

    for (int t = 0; t < TSTEPS; ++t) {
        float acc[R][4];                 // a1 (task A) or a2 (task B)
        float a3[R];
        if (taskA) {
            // ---- task A: a1 = c1 + h2@W1 ; a3 = b2 + h2@W2^T
            #pragma unroll
            for (int i = 0; i < R; ++i) {
                F4 cv; cv.v = *(const float4*)&c1L[(r0 + i) * D1 + j0];
                #pragma unroll
                for (int l = 0; l < 4; ++l) acc[i][l] = cv.f[l];
                a3[i] = b2r;
            }
            // depth-1 weight pipeline: X holds chunk c0's weights, Y c1's.
            F4 waX[4], waY[4];
            #pragma unroll
            for (int kk = 0; kk < 4; ++kk)       // preload chunk 0 (co = jg<<2)
                waX[kk].v = *(const float4*)&W1L[kk * D1 + (jg << 2)];
            for (int cp = 0; cp < 16; ++cp) {
                const int c0 = 2 * cp, c1 = c0 + 1;
                const int k0 = c0 << 2, k1 = k0 + 4;
                {   // prefetch weights for c1
                    const int co = (jg ^ c1) << 2;
                    #pragma unroll
                    for (int kk = 0; kk < 4; ++kk)
                        waY[kk].v = *(const float4*)&W1L[(k1 + kk) * D1 + co];
                }
                {   // chunk c0: state + w2r just-in-time, FMA with waX
                    F4 p2[R], w2r;
                    #pragma unroll
                    for (int i = 0; i < R; ++i)
                        p2[i].v = *(const float4*)&h2L[(r0 + i) * D1 + k0];
                    w2r.v = *(const float4*)(W2 + (size_t)jg3 * D1 + k0);
                    #pragma unroll
                    for (int kk = 0; kk < 4; ++kk)
                        #pragma unroll
                        for (int i = 0; i < R; ++i) {
                            #pragma unroll
                            for (int l = 0; l < 4; ++l)
                                acc[i][l] = fmaf(p2[i].f[kk], waX[kk].f[l], acc[i][l]);
                            a3[i] = fmaf(p2[i].f[kk], w2r.f[kk], a3[i]);
                        }
                }
                {   // prefetch weights for next pair's first chunk (clamp @31)
                    const int cn = (cp == 15) ? 31 : c0 + 2;
                    const int kn = cn << 2, co = (jg ^ cn) << 2;
                    #pragma unroll
                    for (int kk = 0; kk < 4; ++kk)
                        waX[kk].v = *(const float4*)&W1L[(kn + kk) * D1 + co];
                }
                {   // chunk c1: FMA with waY
                    F4 p2[R], w2r;
                    #pragma unroll
                    for (int i = 0; i < R; ++i)
                        p2[i].v = *(const float4*)&h2L[(r0 + i) * D1 + k1];
                    w2r.v = *(const float4*)(W2 + (size_t)jg3 * D1 + k1);
                    #pragma unroll
                    for (int kk = 0; kk < 4; ++kk)
                        #pragma unroll
                        for (int i = 0; i < R; ++i) {
                            #pragma unroll
                            for (int l = 0; l < 4; ++l)
                                acc[i][l] = fmaf(p2[i].f[kk], waY[kk].f[l], acc[i][l]);
                            a3[i] = fmaf(p2[i].f[kk], w2r.f[kk], a3[i]);
                        }
                }
            }
        } else {
            // ---- task B: a2 = b1 + h1@W1^T + h3@W2
            #pragma unroll
            for (int i = 0; i < R; ++i)
                #pragma unroll
                for (int l = 0; l < 4; ++l) acc[i][l] = b1r[l];
            F4 wbX[4], wbY[4];
            #pragma unroll
            for (int l = 0; l < 4; ++l)          // preload chunk 0 (co = jg<<2)
                wbX[l].v = *(const float4*)&W1L[(j0 + l) * D1 + (jg << 2)];
            for (int cp = 0; cp < 16; ++cp) {
                const int c0 = 2 * cp, c1 = c0 + 1;
                const int k0 = c0 << 2, k1 = k0 + 4;
                {   // prefetch weights for c1
                    const int co = (jg ^ c1) << 2;
                    #pragma unroll
                    for (int l = 0; l < 4; ++l)
                        wbY[l].v = *(const float4*)&W1L[(j0 + l) * D1 + co];
                }
                {   // chunk c0
                    F4 p1[R];
                    #pragma unroll
                    for (int i = 0; i < R; ++i)
                        p1[i].v = *(const float4*)&h1L[(r0 + i) * D1 + k0];
                    #pragma unroll
                    for (int kk = 0; kk < 4; ++kk)
                        #pragma unroll
                        for (int i = 0; i < R; ++i)
                            #pragma unroll
                            for (int l = 0; l < 4; ++l)
                                acc[i][l] = fmaf(p1[i].f[kk], wbX[l].f[kk], acc[i][l]);
                }
                {   // prefetch weights for next pair's first chunk (clamp @31)
                    const int cn = (cp == 15) ? 31 : c0 + 2;
                    const int co = (jg ^ cn) << 2;
                    #pragma unroll
                    for (int l = 0; l < 4; ++l)
                        wbX[l].v = *(const float4*)&W1L[(j0 + l) * D1 + co];
                }
                {   // chunk c1
                    F4 p1[R];
                    #pragma unroll
                    for (int i = 0; i < R; ++i)
                        p1[i].v = *(const float4*)&h1L[(r0 + i) * D1 + k1];
                    #pragma unroll
                    for (int kk = 0; kk < 4; ++kk)
                        #pragma unroll
                        for (int i = 0; i < R; ++i)
                            #pragma unroll
                            for (int l = 0; l < 4; ++l)
                                acc[i][l] = fmaf(p1[i].f[kk], wbY[l].f[kk], acc[i][l]);
                }
            }
            for (int kk = 0; kk < D3; ++kk) {            // + h3_old @ W2
                F4 wc; wc.v = *(const float4*)(W2 + (size_t)kk * D1 + j0);
                #pragma unroll
                for (int i = 0; i < R; ++i) {
                    float h3v = out[H3O + (row0 + r0 + i) * D3 + kk];  // bcast L1 hit
                    #pragma unroll
                    for (int l = 0; l < 4; ++l)
                        acc[i][l] = fmaf(h3v, wc.f[l], acc[i][l]);
                }
            }
        }
        __syncthreads();                 // all reads of old state complete
        if (taskA) {
            #pragma unroll
            for (int i = 0; i < R; ++i)
                *(float4*)&h1L[(r0 + i) * D1 + j0] =
                    make_float4(ftanh(acc[i][0]), ftanh(acc[i][1]),
                                ftanh(acc[i][2]), ftanh(acc[i][3]));
            if (jg < D3) {
                #pragma unroll
                for (int i = 0; i < R; ++i)
                    out[H3O + (row0 + r0 + i) * D3 + jg] = ftanh(a3[i]);
            }
        } else {
            #pragma unroll
            for (int i = 0; i < R; ++i)
                *(float4*)&h2L[(r0 + i) * D1 + j0] =
                    make_float4(ftanh(acc[i][0]), ftanh(acc[i][1]),
                                ftanh(acc[i][2]), ftanh(acc[i][3]));
        }
        __syncthreads();                 // new state (incl. out-h3) visible
    }

    // ---------------- epilogue: h1, h2 (h3 already final in out[H3O..])
    for (int q = tid; q < ROWS * 32; q += NT) {
        int r = q >> 5, c4 = q & 31;
        *(float4*)(out + (row0 + r) * D1 + 4 * c4)       = *(const float4*)&h1L[r * D1 + 4 * c4];
        *(float4*)(out + H2O + (row0 + r) * D1 + 4 * c4) = *(const float4*)&h2L[r * D1 + 4 * c4];
    }
}

extern "C" void kernel_launch(void* const* d_in, const int* in_sizes, int n_in,
                              void* d_out, int out_size, void* d_ws, size_t ws_size,
                              hipStream_t stream) {
    // inputs: 0:x 1:y 2:n1 3:n2 4:n3 5:W0 6:b0 7:W1 8:b1 9:W2 10:b2 11:T(=60 hard-coded)
    const float* x  = (const float*)d_in[0];
    const float* n1 = (const float*)d_in[2];
    const float* n2 = (const float*)d_in[3];
    const float* n3 = (const float*)d_in[4];
    const float* W0 = (const float*)d_in[5];
    const float* b0 = (const float*)d_in[6];
    const float* W1 = (const float*)d_in[7];
    const float* b1 = (const float*)d_in[8];
    const float* W2 = (const float*)d_in[9];
    const float* b2 = (const float*)d_in[10];

    k_fused<<<NBLK, NT, 0, stream>>>(x, n1, n2, n3, W0, b0, W1, b1, W2, b2,
                                     (float*)d_out);

    hipError_t e = hipGetLastError();
    if (e != hipSuccess) {   // surface launch error as fp32 1000+e (free on success)
        static float code[4];
        code[0] = code[1] = code[2] = code[3] = 1000.0f + (float)(int)e;
        hipMemcpyAsync(d_out, code, 4 * sizeof(float), hipMemcpyHostToDevice, stream);
    }
}